// Round 8
// baseline (1402.043 us; speedup 1.0000x reference)
//
#include <hip/hip_runtime.h>
#include <hip/hip_bf16.h>
#include <stdint.h>
#include <stddef.h>

// TFT block on MI355X. B=64 T=384 V=12 D=256 H=4 DK=64.
// R11: (1) fgwide -> 32-row tiles + gload_lds staging: 52KB LDS -> 3 blocks/CU
// (TLP covers barrier drains; staging is fire-and-forget so MFMA ratio survives,
// unlike R7's reg-staged attempt). (2) bijective XCD swizzle in gemm_kernel
// (consecutive tiles share A-panels -> L2 hits). (3) causal S-GEMM: fully-masked
// tiles skip loads+MFMA.
typedef __bf16 bf16;
typedef __bf16 bf16x8 __attribute__((ext_vector_type(8)));
typedef __bf16 bf16x4 __attribute__((ext_vector_type(4)));
typedef float  f32x4  __attribute__((ext_vector_type(4)));

#define BTR 24576   // B*T rows
#define EPI_BIAS  1
#define EPI_CVEC  2
#define EPI_ELU   4
#define EPI_ATTN  8
#define EPI_GATE  32   // N=512 permuted pairs -> C = a*sigmoid(g), width N/2
#define EPI_PERM  64   // C-row permutation for building gate-paired weights

typedef const __attribute__((address_space(1))) void gas_void;
typedef __attribute__((address_space(3))) void sas_void;
__device__ __forceinline__ void gload16(const void* g, void* s) {
  __builtin_amdgcn_global_load_lds((gas_void*)g, (sas_void*)s, 16, 0, 0);
}
template<int N> __device__ __forceinline__ void waitvm() {
  asm volatile("s_waitcnt vmcnt(%0)" :: "n"(N) : "memory");
}

// col permutation: a_j -> 32*(j>>4)+(j&15), g_j -> same +16
__device__ __forceinline__ int perm512(int n) {
  return (n < 256) ? (((n >> 4) << 5) + (n & 15))
                   : ((((n - 256) >> 4) << 5) + ((n - 256) & 15) + 16);
}

// ---------------- 128x128 tile bf16 MFMA GEMM, C[m][n] = sum_k A[m][k]*Bt[n][k] ----------------
// KT>0 (bf16-A only, K==KT<=256): full-panel staging, counted vmcnt, raw barriers.
// KT==0: 2-phase double-buffered fallback (AF32 and K>256).
// Block ids remapped with bijective XCD swizzle (m204): same-XCD slots get
// consecutive tiles -> shared A-panels resident in that XCD's L2.
template<int EPI, bool AF32, bool CF32, int KT = 0>
__global__ __launch_bounds__(256, 2)
void gemm_kernel(const void* __restrict__ Av, int lda, long sAh, long sAb,
                 const bf16* __restrict__ Bt, int ldb, long sBh, long sBb,
                 void* __restrict__ Cv, int ldc, long sC,
                 int K, int zdiv,
                 const float* __restrict__ bias, const float* __restrict__ cvec,
                 long sBias)
{
  constexpr int NBUF = (KT > 0) ? (KT / 32) : 2;
  __shared__ __align__(16) bf16 As[NBUF][128 * 32];   // 8 KB per sub-tile
  __shared__ __align__(16) bf16 Bs[NBUF][128 * 32];

  const int tid  = threadIdx.x;
  const int wave = tid >> 6, lane = tid & 63;
  const int wr = wave >> 1, wc = wave & 1;         // 2x2 waves, 64x64 each
  const int quad = lane >> 4, l16 = lane & 15;

  // -------- bijective XCD swizzle --------
  const int gx = gridDim.x, gxy = gridDim.x * gridDim.y;
  const int nwg = gxy * gridDim.z;
  int lin = (blockIdx.z * gridDim.y + blockIdx.y) * gx + blockIdx.x;
  {
    const int q8 = nwg >> 3, r8 = nwg & 7;
    const int xcd = lin & 7, idx = lin >> 3;
    lin = (xcd < r8) ? xcd * (q8 + 1) + idx
                     : r8 * (q8 + 1) + (xcd - r8) * q8 + idx;
  }
  const int z  = lin / gxy;
  const int rem = lin - z * gxy;
  const int by = rem / gx, bx = rem - by * gx;

  const int hh = z / zdiv, bb = z % zdiv;
  const float* AbF = nullptr; const bf16* AbH = nullptr;
  if constexpr (AF32) AbF = (const float*)Av + (long)hh * sAh + (long)bb * sAb;
  else                AbH = (const bf16*)Av  + (long)hh * sAh + (long)bb * sAb;
  const bf16* Bb = Bt + (long)hh * sBh + (long)bb * sBb;
  float* CbF = nullptr; bf16* CbH = nullptr;
  if constexpr (CF32) CbF = (float*)Cv + (long)z * sC;
  else                CbH = (bf16*)Cv  + (long)z * sC;

  const int rowBase = by * 128;
  const int colBase = bx * 128;

  f32x4 acc[4][4];
#pragma unroll
  for (int i = 0; i < 4; ++i)
#pragma unroll
    for (int j = 0; j < 4; ++j) { acc[i][j][0]=0.f; acc[i][j][1]=0.f; acc[i][j][2]=0.f; acc[i][j][3]=0.f; }

  const int r0 = tid >> 2, kc = tid & 3;           // bf16-A / B decode: dest byte = tid*16 (linear)
  const int r1 = tid >> 1, kh = (tid & 1) * 16;    // f32-A decode: 64B half-rows
  const int arow = (wr * 64 + l16) * 32 + quad * 8;
  const int brow = (wc * 64 + l16) * 32 + quad * 8;

  // fully-masked causal tile: skip all loads + MFMA (acc stays 0 -> epilogue writes -1e9)
  const bool skipK = (EPI & EPI_ATTN) && (colBase > rowBase);

  if (!skipK) {
  if constexpr (KT > 0) {
    // ======== full-panel path: issue ALL gloads, counted drains ========
    constexpr int NT = KT / 32;
    char* AsB = (char*)&As[0][0] + wave * 1024;
    char* BsB = (char*)&Bs[0][0] + wave * 1024;
#pragma unroll
    for (int t = 0; t < NT; ++t) {                 // 4 gloads per tile, program order
      const int k0 = t * 32;
      gload16(AbH + (size_t)(rowBase + r0)      * lda + k0 + kc * 8, AsB + t * 8192);
      gload16(AbH + (size_t)(rowBase + 64 + r0) * lda + k0 + kc * 8, AsB + t * 8192 + 4096);
      gload16(Bb  + (size_t)(colBase + r0)      * ldb + k0 + kc * 8, BsB + t * 8192);
      gload16(Bb  + (size_t)(colBase + 64 + r0) * ldb + k0 + kc * 8, BsB + t * 8192 + 4096);
    }
#define FP_TILE(T)                                                                 \
    if constexpr ((T) < NT) {                                                      \
      waitvm<(NT - 1 - (T)) * 4>();                                                \
      __builtin_amdgcn_s_barrier();                                                \
      const bf16* Asc = &As[(T)][0];                                               \
      const bf16* Bsc = &Bs[(T)][0];                                               \
      bf16x8 af[4], bfv[4];                                                        \
      _Pragma("unroll")                                                            \
      for (int mi = 0; mi < 4; ++mi) af[mi]  = *(const bf16x8*)(Asc + arow + mi * 512); \
      _Pragma("unroll")                                                            \
      for (int ni = 0; ni < 4; ++ni) bfv[ni] = *(const bf16x8*)(Bsc + brow + ni * 512); \
      _Pragma("unroll")                                                            \
      for (int mi = 0; mi < 4; ++mi)                                               \
        _Pragma("unroll")                                                          \
        for (int ni = 0; ni < 4; ++ni)                                             \
          acc[mi][ni] = __builtin_amdgcn_mfma_f32_16x16x32_bf16(af[mi], bfv[ni], acc[mi][ni], 0, 0, 0); \
    }
    FP_TILE(0) FP_TILE(1) FP_TILE(2) FP_TILE(3)
    FP_TILE(4) FP_TILE(5) FP_TILE(6) FP_TILE(7)
#undef FP_TILE
  } else {
    // ======== 2-phase double-buffered fallback ========
    char* AsW = (char*)&As[0][0] + wave * 1024;
    char* BsW = (char*)&Bs[0][0] + wave * 1024;
    f32x4 pf0, pf1, pf2, pf3;
    const int nt = K >> 5;
    int cur = 0;

    if constexpr (AF32) {
      const float* p = AbF + (size_t)(rowBase + r1) * lda + kh;
      pf0 = *(const f32x4*)(p);     pf1 = *(const f32x4*)(p + 4);
      pf2 = *(const f32x4*)(p + 8); pf3 = *(const f32x4*)(p + 12);
    } else {
      gload16(AbH + (size_t)(rowBase + r0)      * lda + kc * 8, AsW);
      gload16(AbH + (size_t)(rowBase + 64 + r0) * lda + kc * 8, AsW + 4096);
    }
    gload16(Bb + (size_t)(colBase + r0)      * ldb + kc * 8, BsW);
    gload16(Bb + (size_t)(colBase + 64 + r0) * ldb + kc * 8, BsW + 4096);
    if constexpr (AF32) {
      bf16x8 a0, a1;
#pragma unroll
      for (int e = 0; e < 4; ++e) {
        a0[e] = (bf16)pf0[e]; a0[4 + e] = (bf16)pf1[e];
        a1[e] = (bf16)pf2[e]; a1[4 + e] = (bf16)pf3[e];
      }
      *(bf16x8*)(&As[0][0] + r1 * 32 + kh)     = a0;
      *(bf16x8*)(&As[0][0] + r1 * 32 + kh + 8) = a1;
    }
    __syncthreads();

    for (int t = 0; t < nt; ++t) {
      const int nxt = cur ^ 1;
      if (t + 1 < nt) {
        const int k1 = (t + 1) * 32;
        if constexpr (AF32) {
          const float* p = AbF + (size_t)(rowBase + r1) * lda + k1 + kh;
          pf0 = *(const f32x4*)(p);     pf1 = *(const f32x4*)(p + 4);
          pf2 = *(const f32x4*)(p + 8); pf3 = *(const f32x4*)(p + 12);
        } else {
          gload16(AbH + (size_t)(rowBase + r0)      * lda + k1 + kc * 8, AsW + nxt * 8192);
          gload16(AbH + (size_t)(rowBase + 64 + r0) * lda + k1 + kc * 8, AsW + nxt * 8192 + 4096);
        }
        gload16(Bb + (size_t)(colBase + r0)      * ldb + k1 + kc * 8, BsW + nxt * 8192);
        gload16(Bb + (size_t)(colBase + 64 + r0) * ldb + k1 + kc * 8, BsW + nxt * 8192 + 4096);
      }

      const bf16* Asc = &As[cur][0];
      const bf16* Bsc = &Bs[cur][0];
      bf16x8 af[4], bfv[4];
#pragma unroll
      for (int mi = 0; mi < 4; ++mi) af[mi]  = *(const bf16x8*)(Asc + arow + mi * 512);
#pragma unroll
      for (int ni = 0; ni < 4; ++ni) bfv[ni] = *(const bf16x8*)(Bsc + brow + ni * 512);
#pragma unroll
      for (int mi = 0; mi < 4; ++mi)
#pragma unroll
        for (int ni = 0; ni < 4; ++ni)
          acc[mi][ni] = __builtin_amdgcn_mfma_f32_16x16x32_bf16(af[mi], bfv[ni], acc[mi][ni], 0, 0, 0);

      if constexpr (AF32) {
        if (t + 1 < nt) {
          bf16x8 a0, a1;
#pragma unroll
          for (int e = 0; e < 4; ++e) {
            a0[e] = (bf16)pf0[e]; a0[4 + e] = (bf16)pf1[e];
            a1[e] = (bf16)pf2[e]; a1[4 + e] = (bf16)pf3[e];
          }
          *(bf16x8*)(&As[nxt][0] + r1 * 32 + kh)     = a0;
          *(bf16x8*)(&As[nxt][0] + r1 * 32 + kh + 8) = a1;
        }
      }
      __syncthreads();
      cur = nxt;
    }
  }
  }  // !skipK

  // epilogue. C/D layout: col = lane&15, row = quad*4 + reg  [m89-verified]
  if constexpr (EPI & EPI_GATE) {
    const float* bp = bias + (size_t)z * sBias;
#pragma unroll
    for (int mi = 0; mi < 4; ++mi) {
#pragma unroll
      for (int nj = 0; nj < 2; ++nj) {
        const int ni = nj * 2;
        const int pa = colBase + wc * 64 + ni * 16 + l16;
        const int j  = (colBase >> 1) + wc * 32 + nj * 16 + l16;
        const float ba = bp[pa], bg = bp[pa + 16];
        const int row0 = rowBase + wr * 64 + mi * 16 + quad * 4;
#pragma unroll
        for (int r = 0; r < 4; ++r) {
          float a = acc[mi][ni][r]     + ba;
          float g = acc[mi][ni + 1][r] + bg;
          CbH[(size_t)(row0 + r) * ldc + j] = (bf16)(a / (1.f + __expf(-g)));
        }
      }
    }
    return;
  }
  const int bctx = (EPI & EPI_CVEC) ? (rowBase / 384) : 0;
  const float* bp = (EPI & EPI_BIAS) ? bias + (size_t)z * sBias : nullptr;
#pragma unroll
  for (int mi = 0; mi < 4; ++mi) {
#pragma unroll
    for (int ni = 0; ni < 4; ++ni) {
      const int row0 = rowBase + wr * 64 + mi * 16 + quad * 4;
      const int col  = colBase + wc * 64 + ni * 16 + l16;
      float bv = (EPI & EPI_BIAS) ? bp[col] : 0.f;
      float cv = (EPI & EPI_CVEC) ? cvec[bctx * 256 + col] : 0.f;
#pragma unroll
      for (int r = 0; r < 4; ++r) {
        float v = acc[mi][ni][r] + bv + cv;
        if (EPI & EPI_ELU)  v = v > 0.f ? v : __expf(v) - 1.f;
        if (EPI & EPI_ATTN) { v *= 0.125f; if (col > row0 + r) v = -1e9f; }
        int srow = row0 + r;
        if constexpr (EPI & EPI_PERM) srow = perm512(srow);
        if constexpr (CF32) CbF[(size_t)srow * ldc + col] = v;
        else                CbH[(size_t)srow * ldc + col] = (bf16)v;
      }
    }
  }
}

// ---------------- fg wide kernel: 32 rows x ALL 384 cols per block, K=3072 ----------------
// grid = 768, 3 blocks/CU (52KB LDS). A (x, f32): reg-staged (1 f32x4/thread).
// B = fgW1WsT (L2-resident): gload_lds (fire-and-forget, no repack VALU).
// 2-phase double-buffered LDS; one barrier per k-step; TLP across 3 blocks.
__global__ __launch_bounds__(256, 3)
void fgwide_kernel(const float* __restrict__ A, const bf16* __restrict__ Bt,
                   bf16* __restrict__ C, const float* __restrict__ bias,
                   const float* __restrict__ cvec)
{
  __shared__ __align__(16) bf16 As[2][32 * 32];    // 2 KB per buffer
  __shared__ __align__(16) bf16 Bs[2][384 * 32];   // 24 KB per buffer
  const int tid = threadIdx.x;
  const int wave = tid >> 6, lane = tid & 63;      // wave = column group (96 cols)
  const int quad = lane >> 4, l16 = lane & 15;
  const int rowBase = blockIdx.x * 32;

  f32x4 acc[2][6];
#pragma unroll
  for (int i = 0; i < 2; ++i)
#pragma unroll
    for (int j = 0; j < 6; ++j) { acc[i][j][0]=0.f; acc[i][j][1]=0.f; acc[i][j][2]=0.f; acc[i][j][3]=0.f; }

  const int r1 = tid >> 3, kc1 = (tid & 7) * 4;    // A staging: 4 f32/thread, rows 0..31
  const int arow = l16 * 32 + quad * 8;
  const int brow = (wave * 96 + l16) * 32 + quad * 8;

  char* BsW = (char*)&Bs[0][0] + wave * 1024;      // + c*4096: dest byte = idx*16 (linear)

  f32x4 pf;
  int cur = 0;

  // ---- prologue: tile 0 ----
  {
    pf = *(const f32x4*)(A + (size_t)(rowBase + r1) * 3072 + kc1);
#pragma unroll
    for (int c = 0; c < 6; ++c) {
      const int idx = c * 256 + tid, rb = idx >> 2, kc2 = idx & 3;
      gload16(Bt + (size_t)rb * 3072 + kc2 * 8, BsW + c * 4096);
    }
    bf16x4 av;
#pragma unroll
    for (int e = 0; e < 4; ++e) av[e] = (bf16)pf[e];
    *(bf16x4*)(&As[0][0] + r1 * 32 + kc1) = av;
  }
  __syncthreads();

  for (int t = 0; t < 96; ++t) {
    const int nxt = cur ^ 1;
    if (t + 1 < 96) {
      const int k1 = (t + 1) * 32;
      pf = *(const f32x4*)(A + (size_t)(rowBase + r1) * 3072 + k1 + kc1);
#pragma unroll
      for (int c = 0; c < 6; ++c) {
        const int idx = c * 256 + tid, rb = idx >> 2, kc2 = idx & 3;
        gload16(Bt + (size_t)rb * 3072 + k1 + kc2 * 8, BsW + nxt * 24576 + c * 4096);
      }
    }

    const bf16* Asc = &As[cur][0];
    const bf16* Bsc = &Bs[cur][0];
    bf16x8 af[2], bfv[6];
#pragma unroll
    for (int mi = 0; mi < 2; ++mi) af[mi]  = *(const bf16x8*)(Asc + arow + mi * 512);
#pragma unroll
    for (int ni = 0; ni < 6; ++ni) bfv[ni] = *(const bf16x8*)(Bsc + brow + ni * 512);
#pragma unroll
    for (int mi = 0; mi < 2; ++mi)
#pragma unroll
      for (int ni = 0; ni < 6; ++ni)
        acc[mi][ni] = __builtin_amdgcn_mfma_f32_16x16x32_bf16(af[mi], bfv[ni], acc[mi][ni], 0, 0, 0);

    if (t + 1 < 96) {                              // A arrived during MFMA; write late
      bf16x4 av;
#pragma unroll
      for (int e = 0; e < 4; ++e) av[e] = (bf16)pf[e];
      *(bf16x4*)(&As[nxt][0] + r1 * 32 + kc1) = av;
    }
    __syncthreads();
    cur = nxt;
  }

  const int bctx = rowBase / 384;   // 32-row tile never crosses a b boundary
#pragma unroll
  for (int mi = 0; mi < 2; ++mi) {
#pragma unroll
    for (int ni = 0; ni < 6; ++ni) {
      const int col = wave * 96 + ni * 16 + l16;
      const bool act = (wave * 96 + ni * 16) < 256;  // fragment-uniform
      const float bv = bias[col];
      const float cv = act ? cvec[bctx * 256 + col] : 0.f;
      const int row0 = rowBase + mi * 16 + quad * 4;
#pragma unroll
      for (int r = 0; r < 4; ++r) {
        float v = acc[mi][ni][r] + bv + cv;
        if (act) v = v > 0.f ? v : __expf(v) - 1.f;
        C[(size_t)(row0 + r) * 384 + col] = (bf16)v;
      }
    }
  }
}

// ---------------- prep: weight transposes / pads / plain casts (f32 -> bf16), one launch ----------------
__global__ void prep_kernel(
    const float* fgW1, const float* fgWs, const float* fgW2, const float* fgWg,
    const float* fgb1, const float* fgbs,
    const float* svW1, const float* svWg, const float* svW2,
    const float* enW1, const float* enWg, const float* enW2,
    const float* Wq, const float* Wk, const float* Wv, const float* Wo,
    bf16* fgW1WsT, bf16* fgWgPT, bf16* fgW2C, float* bias384,
    bf16* svW1T, bf16* svWgT, bf16* svW2C,
    bf16* enW1T, bf16* enWgT, bf16* enW2C,
    bf16* WqkvT, bf16* WoT)
{
  long i = (long)blockIdx.x * 256 + threadIdx.x;
  if (i < 1179648) {               // fused [W1 | Ws(pad12->128)] transposed: 384 x 3072
    int n = i / 3072, k = i % 3072; float v;
    if (n < 256) v = fgW1[(size_t)k * 256 + n];
    else { int nn = n - 256; v = (nn < 12) ? fgWs[(size_t)k * 12 + nn] : 0.f; }
    fgW1WsT[i] = (bf16)v; return; } i -= 1179648;
  if (i < 32768)  { int n = i >> 8, k = i & 255; fgWgPT[i] = (n < 24) ? (bf16)fgWg[k * 24 + n] : (bf16)0.f; return; } i -= 32768;
  if (i < 65536)  { fgW2C[i] = (bf16)fgW2[i]; return; } i -= 65536;
  if (i < 384)    { bias384[i] = (i < 256) ? fgb1[i] : ((i < 268) ? fgbs[i - 256] : 0.f); return; } i -= 384;
  if (i < 786432) { long v = i >> 16, r = i & 65535; int n = r >> 8, k = r & 255; svW1T[i] = (bf16)svW1[(v << 16) + k * 256 + n]; return; } i -= 786432;
  if (i < 1572864){ long v = i >> 17, r = i & 131071; int n = r >> 8, k = r & 255; svWgT[i] = (bf16)svWg[(v << 17) + k * 512 + n]; return; } i -= 1572864;
  if (i < 786432) { svW2C[i] = (bf16)svW2[i]; return; } i -= 786432;
  if (i < 65536)  { int n = i >> 8, k = i & 255; enW1T[i] = (bf16)enW1[k * 256 + n]; return; } i -= 65536;
  if (i < 131072) { int n = i >> 8, k = i & 255; enWgT[i] = (bf16)enWg[k * 512 + n]; return; } i -= 131072;
  if (i < 65536)  { enW2C[i] = (bf16)enW2[i]; return; } i -= 65536;
  if (i < 163840) { int n = i >> 8, k = i & 255; float val;
                    if (n < 256)      val = Wq[(n >> 6) * 16384 + k * 64 + (n & 63)];
                    else if (n < 512) { int nn = n - 256; val = Wk[(nn >> 6) * 16384 + k * 64 + (nn & 63)]; }
                    else if (n < 576) val = Wv[k * 64 + (n - 512)];
                    else              val = 0.f;
                    WqkvT[i] = (bf16)val; return; } i -= 163840;
  if (i < 16384)  { int n = i >> 6, k = i & 63; WoT[i] = (bf16)Wo[k * 256 + n]; }
}

// ---------------- fused bias: bF = b2@Wg + bg (f32 exact); sv/en stored PERMUTED ----------------
__global__ void biasfuse_kernel(const float* fgb2, const float* fgWg, const float* fgbg,
                                const float* svb2, const float* svWg, const float* svbg,
                                const float* enb2, const float* enWg, const float* enbg,
                                float* fgBF, float* svBFP, float* enBFP)
{
  int i = blockIdx.x * 256 + threadIdx.x;
  if (i < 128) {
    float s = 0.f;
    if (i < 24) { s = fgbg[i]; for (int k = 0; k < 256; ++k) s += fgb2[k] * fgWg[k * 24 + i]; }
    fgBF[i] = s; return; } i -= 128;
  if (i < 6144) {
    int v = i >> 9, n = i & 511;
    float s = svbg[v * 512 + n];
    const float* W = svWg + (size_t)v * 131072;
    const float* b2 = svb2 + v * 256;
    for (int k = 0; k < 256; ++k) s += b2[k] * W[k * 512 + n];
    svBFP[v * 512 + perm512(n)] = s; return; } i -= 6144;
  if (i < 512) {
    float s = enbg[i];
    for (int k = 0; k < 256; ++k) s += enb2[k] * enWg[k * 512 + i];
    enBFP[perm512(i)] = s; }
}

// ---------------- cvec[b][n] = context[b] @ Wc  (fg / en), all f32 ----------------
__global__ void cvec_kernel(const float* __restrict__ ctx, const float* __restrict__ WcFg,
                            const float* __restrict__ WcEn, float* __restrict__ outFg,
                            float* __restrict__ outEn) {
  int b = blockIdx.x, n = threadIdx.x;
  const float* Wc = blockIdx.y ? WcEn : WcFg;
  float* o = blockIdx.y ? outEn : outFg;
  float acc = 0.f;
  for (int d = 0; d < 256; ++d) acc += ctx[b * 256 + d] * Wc[d * 256 + n];
  o[b * 256 + n] = acc;
}

// ---------------- lnsm12: gate + w = softmax(LN(skip + gated)) over V=12 ----------------
__global__ void lnsm12_kernel(const bf16* __restrict__ B384, const bf16* __restrict__ GP,
                              const float* __restrict__ lng, const float* __restrict__ lnb,
                              float* __restrict__ w) {
  int r = blockIdx.x * 256 + threadIdx.x;
  if (r >= BTR) return;
  float y[12]; float m = 0.f;
#pragma unroll
  for (int j = 0; j < 12; ++j) {
    float a = (float)GP[(size_t)r * 128 + j];
    float g = (float)GP[(size_t)r * 128 + 12 + j];
    float gated = a / (1.f + __expf(-g));
    y[j] = (float)B384[(size_t)r * 384 + 256 + j] + gated; m += y[j];
  }
  m *= (1.f / 12.f);
  float var = 0.f;
#pragma unroll
  for (int j = 0; j < 12; ++j) { float d = y[j] - m; var += d * d; }
  var *= (1.f / 12.f);
  float rstd = rsqrtf(var + 1e-5f);
  float mx = -1e30f;
#pragma unroll
  for (int j = 0; j < 12; ++j) { y[j] = (y[j] - m) * rstd * lng[j] + lnb[j]; mx = fmaxf(mx, y[j]); }
  float s = 0.f;
#pragma unroll
  for (int j = 0; j < 12; ++j) { y[j] = __expf(y[j] - mx); s += y[j]; }
  float inv = 1.f / s;
#pragma unroll
  for (int j = 0; j < 12; ++j) w[r * 12 + j] = y[j] * inv;
}

// ---------------- block (256-thr) reduce of two sums ----------------
__device__ __forceinline__ void block_sum2(float a, float b, float& oa, float& ob) {
#pragma unroll
  for (int o = 32; o; o >>= 1) { a += __shfl_xor(a, o); b += __shfl_xor(b, o); }
  __shared__ float ra[4], rb[4];
  int w = threadIdx.x >> 6;
  if ((threadIdx.x & 63) == 0) { ra[w] = a; rb[w] = b; }
  __syncthreads();
  oa = ra[0] + ra[1] + ra[2] + ra[3];
  ob = rb[0] + rb[1] + rb[2] + rb[3];
  __syncthreads();
}

// ---------------- per-variable GRN tail for 4 vars: LN + weighted acc (gated precomputed) ----------------
__global__ __launch_bounds__(256)
void selacc4_kernel(const bf16* __restrict__ GATED, const float* __restrict__ x,
                    const float* __restrict__ w, const float* __restrict__ lng,
                    const float* __restrict__ lnb, float* __restrict__ sel,
                    bf16* __restrict__ selb, int v0, int isFirst, int isLast) {
  int r = blockIdx.x, d = threadIdx.x;
  float acc = isFirst ? 0.f : sel[(size_t)r * 256 + d];
#pragma unroll
  for (int vv = 0; vv < 4; ++vv) {
    int v = v0 + vv;
    float gated = (float)GATED[(size_t)vv * ((size_t)BTR * 256) + (size_t)r * 256 + d];
    float y = x[(size_t)r * 3072 + v * 256 + d] + gated;
    float s1, s2;
    block_sum2(y, y * y, s1, s2);
    float mean = s1 * (1.f / 256.f);
    float var  = s2 * (1.f / 256.f) - mean * mean;
    float val  = (y - mean) * rsqrtf(var + 1e-5f) * lng[v * 256 + d] + lnb[v * 256 + d];
    acc += w[r * 12 + v] * val;
  }
  if (isLast) selb[(size_t)r * 256 + d] = (bf16)acc;
  else        sel[(size_t)r * 256 + d] = acc;
}

// ---------------- enrichment GRN tail: LN(skip + gated) -> enr (gated precomputed) ----------------
__global__ __launch_bounds__(256)
void enrln_kernel(const bf16* __restrict__ GATED, const bf16* __restrict__ skip,
                  const float* __restrict__ lng, const float* __restrict__ lnb,
                  bf16* __restrict__ out) {
  int r = blockIdx.x, d = threadIdx.x;
  float gated = (float)GATED[(size_t)r * 256 + d];
  float y = (float)skip[(size_t)r * 256 + d] + gated;
  float s1, s2;
  block_sum2(y, y * y, s1, s2);
  float mean = s1 * (1.f / 256.f);
  float var = s2 * (1.f / 256.f) - mean * mean;
  float norm = (y - mean) * rsqrtf(var + 1e-5f);
  out[(size_t)r * 256 + d] = (bf16)(norm * lng[d] + lnb[d]);
}

// ---------------- Pbar[b,q,:] = (1/4) sum_h softmax(S[h,b,q,:]) — wave per row ----------------
__global__ __launch_bounds__(256)
void softmax_avg_kernel(const bf16* __restrict__ S, bf16* __restrict__ P) {
  const int wv = threadIdx.x >> 6, lane = threadIdx.x & 63;
  const int bq = blockIdx.x * 4 + wv;
  const int b = bq / 384, q = bq % 384;
  float pb[6];
#pragma unroll
  for (int e = 0; e < 6; ++e) pb[e] = 0.f;
  for (int h = 0; h < 4; ++h) {
    const bf16* row = S + ((size_t)((h * 64 + b) * 384 + q)) * 384;
    float v[6]; float m = -1e30f;
#pragma unroll
    for (int e = 0; e < 6; ++e) { v[e] = (float)row[lane + e * 64]; m = fmaxf(m, v[e]); }
#pragma unroll
    for (int o = 32; o; o >>= 1) m = fmaxf(m, __shfl_xor(m, o));
    float l = 0.f;
#pragma unroll
    for (int e = 0; e < 6; ++e) { v[e] = __expf(v[e] - m); l += v[e]; }
#pragma unroll
    for (int o = 32; o; o >>= 1) l += __shfl_xor(l, o);
    float inv = 1.f / l;
#pragma unroll
    for (int e = 0; e < 6; ++e) pb[e] += v[e] * inv;
  }
  bf16* out = P + (size_t)bq * 384;
#pragma unroll
  for (int e = 0; e < 6; ++e) out[lane + e * 64] = (bf16)(0.25f * pb[e]);
}

// ================= host side =================
template<int EPI, bool AF32, bool CF32, int KT = 0>
static inline void rungemm(hipStream_t s,
    const void* A, int lda, const bf16* Bt, int ldb, void* C, int ldc,
    int M, int N, int K,
    const float* bias = nullptr, const float* cvec = nullptr,
    int Z = 1, int zdiv = 1,
    long sAh = 0, long sAb = 0, long sBh = 0, long sBb = 0, long sC = 0, long sBias = 0)
{
  dim3 grid(N / 128, M / 128, Z);
  gemm_kernel<EPI, AF32, CF32, KT><<<grid, 256, 0, s>>>(A, lda, sAh, sAb, Bt, ldb, sBh, sBb, C, ldc, sC, K, zdiv, bias, cvec, sBias);
}

extern "C" void kernel_launch(void* const* d_in, const int* in_sizes, int n_in,
                              void* d_out, int out_size, void* d_ws, size_t ws_size,
                              hipStream_t stream)
{
  (void)in_sizes; (void)n_in; (void)out_size;
  const float* x      = (const float*)d_in[0];
  const float* ctx    = (const float*)d_in[1];
  const float* fg_W1  = (const float*)d_in[2];
  const float* fg_b1  = (const float*)d_in[3];
  const float* fg_Wc  = (const float*)d_in[4];
  const float* fg_W2  = (const float*)d_in[5];
  const float* fg_b2  = (const float*)d_in[6];
  const float* fg_Wg  = (const float*)d_in[7];
  const float* fg_bg  = (const float*)d_in[8];
  const float* fg_Ws  = (const float*)d_in[9];
  const float* fg_bs  = (const float*)d_in[10];
  const float* fg_lng = (const float*)d_in[11];
  const float* fg_lnb = (const float*)d_in[12];
  const float* sv_W1  = (const float*)d_in[13];
  const float* sv_b1  = (const float*)d_in[14];
  const float* sv_W2  = (const float*)d_in[15];
  const float* sv_b2  = (const float*)d_in[16];
  const float* sv_Wg  = (const float*)d_in[17];
  const float* sv_bg  = (const float*)d_in[18];
  const float* sv_lng = (const float*)d_in[19];
  const float* sv_lnb = (const float*)d_in[20];
  const float* en_W1  = (const float*)d_in[21];
  const float* en_b1  = (const float*)d_in[22];
  const float* en_Wc  = (const float*)d_in[23];
  const float* en_W2  = (const float*)d_in[24];
  const float* en_b2  = (const float*)d_in[25];
  const float* en_Wg  = (const float*)d_in[26];
  const float* en_bg  = (const float*)d_in[27];
  const float* en_lng = (const float*)d_in[28];
  const float* en_lnb = (const float*)d_in[29];
  const float* Wq     = (const float*)d_in[30];
  const float* Wk     = (const float*)d_in[31];
  const float* Wv     = (const float*)d_in[32];
  const float* Wo     = (const float*)d_in[33];

  // -------- workspace layout (bytes) --------
  static constexpr size_t OFF_FGW1WST = 0;                          // 384x3072 bf16
  static constexpr size_t OFF_FGWGPT  = OFF_FGW1WST + 2359296;      // 128x256 bf16
  static constexpr size_t OFF_FGW2C   = OFF_FGWGPT  + 65536;        // 256x256 bf16
  static constexpr size_t OFF_FGW2GT  = OFF_FGW2C   + 131072;       // 128x256 bf16
  static constexpr size_t OFF_BIAS384 = OFF_FGW2GT  + 65536;        // 384 f32
  static constexpr size_t OFF_FGBF    = OFF_BIAS384 + 1536;         // 128 f32
  static constexpr size_t OFF_SVW1T   = OFF_FGBF    + 512;          // 12x256x256 bf16
  static constexpr size_t OFF_SVWGT   = OFF_SVW1T   + 1572864;      // 12x512x256 bf16
  static constexpr size_t OFF_SVW2C   = OFF_SVWGT   + 3145728;      // 12x256x256 bf16
  static constexpr size_t OFF_SVW2GPT = OFF_SVW2C   + 1572864;      // 12x512x256 bf16 (row-permuted)
  static constexpr size_t OFF_SVBFP   = OFF_SVW2GPT + 3145728;      // 12x512 f32 (permuted)
  static constexpr size_t OFF_ENW1T   = OFF_SVBFP   + 24576;        // 256x256 bf16
  static constexpr size_t OFF_ENWGT   = OFF_ENW1T   + 131072;       // 512x256 bf16
  static constexpr size_t OFF_ENW2C   = OFF_ENWGT   + 262144;       // 256x256 bf16
  static constexpr size_t OFF_ENW2GPT = OFF_ENW2C   + 131072;       // 512x256 bf16 (row-permuted)
  static constexpr size_t OFF_ENBFP   = OFF_ENW2GPT + 262144;       // 512 f32 (permuted)
  static constexpr size_t OFF_WQKVT   = OFF_ENBFP   + 2048;         // 640x256 bf16
  static constexpr size_t OFF_WOT     = OFF_WQKVT   + 327680;       // 256x64 bf16
  static constexpr size_t OFF_CVECFG  = OFF_WOT     + 32768;        // 64x256 f32
  static constexpr size_t OFF_CVECEN  = OFF_CVECFG  + 65536;
  static constexpr size_t ARENA       = OFF_CVECEN  + 65536;        // = 13,365,248
  static constexpr size_t WS_NEEDED = ARENA + 152174592;            // ~158 MB

  if (ws_size < WS_NEEDED) return;  // fail cleanly

  char* ws = (char*)d_ws;
  bf16*  fgW1WsT = (bf16*)(ws + OFF_FGW1WST);
  bf16*  fgWgPT  = (bf16*)(ws + OFF_FGWGPT);
  bf16*  fgW2C   = (bf16*)(ws + OFF_FGW2C);
  bf16*  fgW2gT  = (bf16*)(ws + OFF_FGW2GT);
  float* bias384 = (float*)(ws + OFF_BIAS384);
  float* fgBF    = (float*)(ws + OFF_FGBF);
  bf16*  svW1T   = (bf16*)(ws + OFF_SVW1T);
  bf16*  svWgT   = (bf16*)(ws + OFF_SVWGT);
  bf16*  svW2C   = (bf16*)(ws + OFF_SVW2C);
  bf16*  svW2gPT = (bf16*)(ws + OFF_SVW2GPT);
  float* svBFP   = (float*)(ws + OFF_SVBFP);
  bf16*  enW1T   = (bf16*)(ws + OFF_ENW1T);
  bf16*  enWgT   = (bf16*)(ws + OFF_ENWGT);
  bf16*  enW2C   = (bf16*)(ws + OFF_ENW2C);
  bf16*  enW2gPT = (bf16*)(ws + OFF_ENW2GPT);
  float* enBFP   = (float*)(ws + OFF_ENBFP);
  bf16*  WqkvT   = (bf16*)(ws + OFF_WQKVT);
  bf16*  WoT     = (bf16*)(ws + OFF_WOT);
  float* cvecFg  = (float*)(ws + OFF_CVECFG);
  float* cvecEn  = (float*)(ws + OFF_CVECEN);
  char*  ar      = ws + ARENA;
  float* sel     = (float*)(ar + 0);
  bf16*  selb    = (bf16*)(ar + 25165824);
  float* wbuf    = (float*)(ar + 37748736);
  bf16*  H1G     = (bf16*)(ar + 38928384);
  bf16*  BUF384  = (bf16*)(ar + 38928384);
  bf16*  GPAD    = (bf16*)(ar + 57802752);
  bf16*  H1EN    = (bf16*)(ar + 38928384);
  bf16*  GATED   = (bf16*)(ar + 89260032);
  bf16*  GATEDEN = (bf16*)(ar + 89260032);
  bf16*  enr     = (bf16*)(ar + 139591680);
  bf16*  QKV     = (bf16*)(ar + 0);
  bf16*  Pbar    = (bf16*)(ar + 38928384);
  bf16*  Sbuf    = (bf16*)(ar + 64094208);
  bf16*  UT      = (bf16*)(ar + 64094208);
  float* out     = (float*)d_out;

  // 1) weight prep
  prep_kernel<<<19010, 256, 0, stream>>>(fg_W1, fg_Ws, fg_W2, fg_Wg, fg_b1, fg_bs,
                                         sv_W1, sv_Wg, sv_W2, en_W1, en_Wg, en_W2,
                                         Wq, Wk, Wv, Wo,
                                         fgW1WsT, fgWgPT, fgW2C, bias384,
                                         svW1T, svWgT, svW2C, enW1T, enWgT, enW2C,
                                         WqkvT, WoT);
  // 2) fused biases (sv/en permuted) + context vectors
  biasfuse_kernel<<<27, 256, 0, stream>>>(fg_b2, fg_Wg, fg_bg, sv_b2, sv_Wg, sv_bg,
                                          en_b2, en_Wg, en_bg, fgBF, svBFP, enBFP);
  cvec_kernel<<<dim3(64, 2), 256, 0, stream>>>(ctx, fg_Wc, en_Wc, cvecFg, cvecEn);

  // 3) combined weights W2g[n][k2] = sum_k Wg[k][n]*W2[k2][k]; sv/en rows stored permuted
  rungemm<0,        false, false, 256>(stream, fgWgPT, 256, fgW2C, 256, fgW2gT, 256, 128, 256, 256);
  rungemm<EPI_PERM, false, false, 256>(stream, svWgT, 256, svW2C, 256, svW2gPT, 256, 512, 256, 256,
                                       nullptr, nullptr, 12, 12, 0, 131072, 0, 65536, 131072);
  rungemm<EPI_PERM, false, false, 256>(stream, enWgT, 256, enW2C, 256, enW2gPT, 256, 512, 256, 256);

  // 4) flattened GRN: wide-tile fused [h1 | skip] GEMM (x read once), g GEMM, LN+softmax
  fgwide_kernel<<<768, 256, 0, stream>>>(x, fgW1WsT, BUF384, bias384, cvecFg);
  rungemm<EPI_BIAS, false, false, 256>(stream, BUF384, 384, fgW2gT, 256, GPAD, 128, BTR, 128, 256, fgBF);
  lnsm12_kernel<<<96, 256, 0, stream>>>(BUF384, GPAD, fg_lng, fg_lnb, wbuf);

  // 5) per-variable GRNs, batched Z=4 (3 groups), gate fused in W2g epilogue
  for (int g = 0; g < 3; ++g) {
    rungemm<EPI_BIAS|EPI_ELU, true, false>(
        stream, x + g * 4 * 256, 3072, svW1T + (size_t)g * 4 * 65536, 256, H1G, 256, BTR, 256, 256,
        sv_b1 + g * 4 * 256, nullptr, 4, 4, 0, 256, 0, 65536, (long)BTR * 256, 256);
    rungemm<EPI_BIAS|EPI_GATE, false, false, 256>(
        stream, H1G, 256, svW2gPT + (size_t)g * 4 * 131072, 256, GATED, 256, BTR, 512, 256,
        svBFP + g * 4 * 512, nullptr, 4, 4, 0, (long)BTR * 256, 0, 131072, (long)BTR * 256, 512);
    selacc4_kernel<<<BTR, 256, 0, stream>>>(GATED, x, wbuf, sv_lng, sv_lnb, sel, selb,
                                            g * 4, g == 0, g == 2);
  }

  // 6) enrichment GRN (gate fused)
  rungemm<EPI_BIAS|EPI_CVEC|EPI_ELU, false, false, 256>(stream, selb, 256, enW1T, 256, H1EN, 256, BTR, 256, 256, en_b1, cvecEn);
  rungemm<EPI_BIAS|EPI_GATE, false, false, 256>(stream, H1EN, 256, enW2gPT, 256, GATEDEN, 256, BTR, 512, 256, enBFP);
  enrln_kernel<<<BTR, 256, 0, stream>>>(GATEDEN, selb, en_lng, en_lnb, enr);

  // 7) attention
  rungemm<0, false, false, 256>(stream, enr, 256, WqkvT, 256, QKV, 640, BTR, 640, 256);
  rungemm<EPI_ATTN, false, false, 64>(stream, QKV, 640, QKV + 256, 640, Sbuf, 384, 384, 384, 64,
                                      nullptr, nullptr, 256, 64, 64, 245760L, 64, 245760L, 147456L);
  softmax_avg_kernel<<<6144, 256, 0, stream>>>(Sbuf, Pbar);
  // UT[b][d][t] = sum_k Wo[k][d] * vp_b[t][k]  (direct transposed U)
  rungemm<0, false, false, 64>(stream, WoT, 64, QKV + 512, 640, UT, 384, 256, 384, 64,
                               nullptr, nullptr, 64, 64, 0, 0, 0, 245760L, 98304L);
  // out[b] = Pbar[b] @ UT[b]^T, batched over b -> f32 d_out
  rungemm<0, false, true>(stream, Pbar, 384, UT, 384, out, 256, 384, 256, 384,
                          nullptr, nullptr, 64, 1, 147456L, 0, 98304L, 0, 98304L);
}

// Round 9
// 1232.353 us; speedup vs baseline: 1.1377x; 1.1377x over previous
//
#include <hip/hip_runtime.h>
#include <hip/hip_bf16.h>
#include <stdint.h>
#include <stddef.h>

// TFT block on MI355X. B=64 T=384 V=12 D=256 H=4 DK=64.
// R12: (1) fgwide reverted to 64-row R9 form (best measured: 192us).
// (2) KT=256 GEMM path -> 4 ROTATING buffers (64KB LDS = 2 blocks/CU) with
// 3-deep prefetch + counted vmcnt(8/4/0) - R10's version was 128KB = 1 block/CU.
// (3) weight transposes via LDS-tiled coalesced kernel (was 32x-amplified
// strided 4B reads). Keeps R11's XCD swizzle + causal tile skip.
typedef __bf16 bf16;
typedef __bf16 bf16x8 __attribute__((ext_vector_type(8)));
typedef float  f32x4  __attribute__((ext_vector_type(4)));

#define BTR 24576   // B*T rows
#define EPI_BIAS  1
#define EPI_CVEC  2
#define EPI_ELU   4
#define EPI_ATTN  8
#define EPI_GATE  32   // N=512 permuted pairs -> C = a*sigmoid(g), width N/2
#define EPI_PERM  64   // C-row permutation for building gate-paired weights

typedef const __attribute__((address_space(1))) void gas_void;
typedef __attribute__((address_space(3))) void sas_void;
__device__ __forceinline__ void gload16(const void* g, void* s) {
  __builtin_amdgcn_global_load_lds((gas_void*)g, (sas_void*)s, 16, 0, 0);
}
template<int N> __device__ __forceinline__ void waitvm() {
  asm volatile("s_waitcnt vmcnt(%0)" :: "n"(N) : "memory");
}

// col permutation: a_j -> 32*(j>>4)+(j&15), g_j -> same +16
__device__ __forceinline__ int perm512(int n) {
  return (n < 256) ? (((n >> 4) << 5) + (n & 15))
                   : ((((n - 256) >> 4) << 5) + ((n - 256) & 15) + 16);
}

// ---------------- 128x128 tile bf16 MFMA GEMM, C[m][n] = sum_k A[m][k]*Bt[n][k] ----------------
// KT==256 (bf16-A): 4 rotating LDS buffers, 3-deep prefetch, counted vmcnt.
// KT==64: full-panel 2-buffer counted. KT==0: 2-phase double-buffered fallback.
template<int EPI, bool AF32, bool CF32, int KT = 0>
__global__ __launch_bounds__(256, 2)
void gemm_kernel(const void* __restrict__ Av, int lda, long sAh, long sAb,
                 const bf16* __restrict__ Bt, int ldb, long sBh, long sBb,
                 void* __restrict__ Cv, int ldc, long sC,
                 int K, int zdiv,
                 const float* __restrict__ bias, const float* __restrict__ cvec,
                 long sBias)
{
  constexpr int NBUF = (KT == 256) ? 4 : 2;
  __shared__ __align__(16) bf16 As[NBUF][128 * 32];   // 8 KB per sub-tile
  __shared__ __align__(16) bf16 Bs[NBUF][128 * 32];

  const int tid  = threadIdx.x;
  const int wave = tid >> 6, lane = tid & 63;
  const int wr = wave >> 1, wc = wave & 1;         // 2x2 waves, 64x64 each
  const int quad = lane >> 4, l16 = lane & 15;

  // -------- bijective XCD swizzle --------
  const int gx = gridDim.x, gxy = gridDim.x * gridDim.y;
  const int nwg = gxy * gridDim.z;
  int lin = (blockIdx.z * gridDim.y + blockIdx.y) * gx + blockIdx.x;
  {
    const int q8 = nwg >> 3, r8 = nwg & 7;
    const int xcd = lin & 7, idx = lin >> 3;
    lin = (xcd < r8) ? xcd * (q8 + 1) + idx
                     : r8 * (q8 + 1) + (xcd - r8) * q8 + idx;
  }
  const int z  = lin / gxy;
  const int rem = lin - z * gxy;
  const int by = rem / gx, bx = rem - by * gx;

  const int hh = z / zdiv, bb = z % zdiv;
  const float* AbF = nullptr; const bf16* AbH = nullptr;
  if constexpr (AF32) AbF = (const float*)Av + (long)hh * sAh + (long)bb * sAb;
  else                AbH = (const bf16*)Av  + (long)hh * sAh + (long)bb * sAb;
  const bf16* Bb = Bt + (long)hh * sBh + (long)bb * sBb;
  float* CbF = nullptr; bf16* CbH = nullptr;
  if constexpr (CF32) CbF = (float*)Cv + (long)z * sC;
  else                CbH = (bf16*)Cv  + (long)z * sC;

  const int rowBase = by * 128;
  const int colBase = bx * 128;

  f32x4 acc[4][4];
#pragma unroll
  for (int i = 0; i < 4; ++i)
#pragma unroll
    for (int j = 0; j < 4; ++j) { acc[i][j][0]=0.f; acc[i][j][1]=0.f; acc[i][j][2]=0.f; acc[i][j][3]=0.f; }

  const int r0 = tid >> 2, kc = tid & 3;           // bf16-A / B decode: dest byte = tid*16 (linear)
  const int r1 = tid >> 1, kh = (tid & 1) * 16;    // f32-A decode: 64B half-rows
  const int arow = (wr * 64 + l16) * 32 + quad * 8;
  const int brow = (wc * 64 + l16) * 32 + quad * 8;

  // fully-masked causal tile: skip all loads + MFMA (acc stays 0 -> epilogue writes -1e9)
  const bool skipK = (EPI & EPI_ATTN) && (colBase > rowBase);

  if (!skipK) {
  if constexpr (KT == 256) {
    // ======== rotating 4-buffer path: 3-deep prefetch, counted drains ========
    char* AsB = (char*)&As[0][0] + wave * 1024;
    char* BsB = (char*)&Bs[0][0] + wave * 1024;
#define RT_ISSUE(T)                                                                \
    { const int k0 = (T) * 32; char* ad = AsB + ((T) & 3) * 8192;                  \
      char* bd = BsB + ((T) & 3) * 8192;                                           \
      gload16(AbH + (size_t)(rowBase + r0)      * lda + k0 + kc * 8, ad);          \
      gload16(AbH + (size_t)(rowBase + 64 + r0) * lda + k0 + kc * 8, ad + 4096);   \
      gload16(Bb  + (size_t)(colBase + r0)      * ldb + k0 + kc * 8, bd);          \
      gload16(Bb  + (size_t)(colBase + 64 + r0) * ldb + k0 + kc * 8, bd + 4096); }
    RT_ISSUE(0) RT_ISSUE(1) RT_ISSUE(2)
#define RT_TILE(T)                                                                 \
    {                                                                              \
      waitvm<((T) < 6) ? 8 : (((T) == 6) ? 4 : 0)>();                              \
      __builtin_amdgcn_s_barrier();                                                \
      if constexpr ((T) < 5) RT_ISSUE((T) + 3)                                     \
      const bf16* Asc = &As[(T) & 3][0];                                           \
      const bf16* Bsc = &Bs[(T) & 3][0];                                           \
      bf16x8 af[4], bfv[4];                                                        \
      _Pragma("unroll")                                                            \
      for (int mi = 0; mi < 4; ++mi) af[mi]  = *(const bf16x8*)(Asc + arow + mi * 512); \
      _Pragma("unroll")                                                            \
      for (int ni = 0; ni < 4; ++ni) bfv[ni] = *(const bf16x8*)(Bsc + brow + ni * 512); \
      _Pragma("unroll")                                                            \
      for (int mi = 0; mi < 4; ++mi)                                               \
        _Pragma("unroll")                                                          \
        for (int ni = 0; ni < 4; ++ni)                                             \
          acc[mi][ni] = __builtin_amdgcn_mfma_f32_16x16x32_bf16(af[mi], bfv[ni], acc[mi][ni], 0, 0, 0); \
    }
    RT_TILE(0) RT_TILE(1) RT_TILE(2) RT_TILE(3)
    RT_TILE(4) RT_TILE(5) RT_TILE(6) RT_TILE(7)
#undef RT_TILE
#undef RT_ISSUE
  } else if constexpr (KT == 64) {
    // ======== small-K full-panel path ========
    char* AsB = (char*)&As[0][0] + wave * 1024;
    char* BsB = (char*)&Bs[0][0] + wave * 1024;
#pragma unroll
    for (int t = 0; t < 2; ++t) {
      const int k0 = t * 32;
      gload16(AbH + (size_t)(rowBase + r0)      * lda + k0 + kc * 8, AsB + t * 8192);
      gload16(AbH + (size_t)(rowBase + 64 + r0) * lda + k0 + kc * 8, AsB + t * 8192 + 4096);
      gload16(Bb  + (size_t)(colBase + r0)      * ldb + k0 + kc * 8, BsB + t * 8192);
      gload16(Bb  + (size_t)(colBase + 64 + r0) * ldb + k0 + kc * 8, BsB + t * 8192 + 4096);
    }
#define FP_TILE(T)                                                                 \
    {                                                                              \
      waitvm<(1 - (T)) * 4>();                                                     \
      __builtin_amdgcn_s_barrier();                                                \
      const bf16* Asc = &As[(T)][0];                                               \
      const bf16* Bsc = &Bs[(T)][0];                                               \
      bf16x8 af[4], bfv[4];                                                        \
      _Pragma("unroll")                                                            \
      for (int mi = 0; mi < 4; ++mi) af[mi]  = *(const bf16x8*)(Asc + arow + mi * 512); \
      _Pragma("unroll")                                                            \
      for (int ni = 0; ni < 4; ++ni) bfv[ni] = *(const bf16x8*)(Bsc + brow + ni * 512); \
      _Pragma("unroll")                                                            \
      for (int mi = 0; mi < 4; ++mi)                                               \
        _Pragma("unroll")                                                          \
        for (int ni = 0; ni < 4; ++ni)                                             \
          acc[mi][ni] = __builtin_amdgcn_mfma_f32_16x16x32_bf16(af[mi], bfv[ni], acc[mi][ni], 0, 0, 0); \
    }
    FP_TILE(0) FP_TILE(1)
#undef FP_TILE
  } else {
    // ======== 2-phase double-buffered fallback (AF32 / generic K) ========
    char* AsW = (char*)&As[0][0] + wave * 1024;
    char* BsW = (char*)&Bs[0][0] + wave * 1024;
    f32x4 pf0, pf1, pf2, pf3;
    const int nt = K >> 5;
    int cur = 0;

    if constexpr (AF32) {
      const float* p = AbF + (size_t)(rowBase + r1) * lda + kh;
      pf0 = *(const f32x4*)(p);     pf1 = *(const f32x4*)(p + 4);
      pf2 = *(const f32x4*)(p + 8); pf3 = *(const f32x4*)(p + 12);
    } else {
      gload16(AbH + (size_t)(rowBase + r0)      * lda + kc * 8, AsW);
      gload16(AbH + (size_t)(rowBase + 64 + r0) * lda + kc * 8, AsW + 4096);
    }
    gload16(Bb + (size_t)(colBase + r0)      * ldb + kc * 8, BsW);
    gload16(Bb + (size_t)(colBase + 64 + r0) * ldb + kc * 8, BsW + 4096);
    if constexpr (AF32) {
      bf16x8 a0, a1;
#pragma unroll
      for (int e = 0; e < 4; ++e) {
        a0[e] = (bf16)pf0[e]; a0[4 + e] = (bf16)pf1[e];
        a1[e] = (bf16)pf2[e]; a1[4 + e] = (bf16)pf3[e];
      }
      *(bf16x8*)(&As[0][0] + r1 * 32 + kh)     = a0;
      *(bf16x8*)(&As[0][0] + r1 * 32 + kh + 8) = a1;
    }
    __syncthreads();

    for (int t = 0; t < nt; ++t) {
      const int nxt = cur ^ 1;
      if (t + 1 < nt) {
        const int k1 = (t + 1) * 32;
        if constexpr (AF32) {
          const float* p = AbF + (size_t)(rowBase + r1) * lda + k1 + kh;
          pf0 = *(const f32x4*)(p);     pf1 = *(const f32x4*)(p + 4);
          pf2 = *(const f32x4*)(p + 8); pf3 = *(const f32x4*)(p + 12);
        } else {
          gload16(AbH + (size_t)(rowBase + r0)      * lda + k1 + kc * 8, AsW + nxt * 8192);
          gload16(AbH + (size_t)(rowBase + 64 + r0) * lda + k1 + kc * 8, AsW + nxt * 8192 + 4096);
        }
        gload16(Bb + (size_t)(colBase + r0)      * ldb + k1 + kc * 8, BsW + nxt * 8192);
        gload16(Bb + (size_t)(colBase + 64 + r0) * ldb + k1 + kc * 8, BsW + nxt * 8192 + 4096);
      }

      const bf16* Asc = &As[cur][0];
      const bf16* Bsc = &Bs[cur][0];
      bf16x8 af[4], bfv[4];
#pragma unroll
      for (int mi = 0; mi < 4; ++mi) af[mi]  = *(const bf16x8*)(Asc + arow + mi * 512);
#pragma unroll
      for (int ni = 0; ni < 4; ++ni) bfv[ni] = *(const bf16x8*)(Bsc + brow + ni * 512);
#pragma unroll
      for (int mi = 0; mi < 4; ++mi)
#pragma unroll
        for (int ni = 0; ni < 4; ++ni)
          acc[mi][ni] = __builtin_amdgcn_mfma_f32_16x16x32_bf16(af[mi], bfv[ni], acc[mi][ni], 0, 0, 0);

      if constexpr (AF32) {
        if (t + 1 < nt) {
          bf16x8 a0, a1;
#pragma unroll
          for (int e = 0; e < 4; ++e) {
            a0[e] = (bf16)pf0[e]; a0[4 + e] = (bf16)pf1[e];
            a1[e] = (bf16)pf2[e]; a1[4 + e] = (bf16)pf3[e];
          }
          *(bf16x8*)(&As[nxt][0] + r1 * 32 + kh)     = a0;
          *(bf16x8*)(&As[nxt][0] + r1 * 32 + kh + 8) = a1;
        }
      }
      __syncthreads();
      cur = nxt;
    }
  }
  }  // !skipK

  // epilogue. C/D layout: col = lane&15, row = quad*4 + reg  [m89-verified]
  if constexpr (EPI & EPI_GATE) {
    const float* bp = bias + (size_t)z * sBias;
#pragma unroll
    for (int mi = 0; mi < 4; ++mi) {
#pragma unroll
      for (int nj = 0; nj < 2; ++nj) {
        const int ni = nj * 2;
        const int pa = colBase + wc * 64 + ni * 16 + l16;
        const int j  = (colBase >> 1) + wc * 32 + nj * 16 + l16;
        const float ba = bp[pa], bg = bp[pa + 16];
        const int row0 = rowBase + wr * 64 + mi * 16 + quad * 4;
#pragma unroll
        for (int r = 0; r < 4; ++r) {
          float a = acc[mi][ni][r]     + ba;
          float g = acc[mi][ni + 1][r] + bg;
          CbH[(size_t)(row0 + r) * ldc + j] = (bf16)(a / (1.f + __expf(-g)));
        }
      }
    }
    return;
  }
  const int bctx = (EPI & EPI_CVEC) ? (rowBase / 384) : 0;
  const float* bp = (EPI & EPI_BIAS) ? bias + (size_t)z * sBias : nullptr;
#pragma unroll
  for (int mi = 0; mi < 4; ++mi) {
#pragma unroll
    for (int ni = 0; ni < 4; ++ni) {
      const int row0 = rowBase + wr * 64 + mi * 16 + quad * 4;
      const int col  = colBase + wc * 64 + ni * 16 + l16;
      float bv = (EPI & EPI_BIAS) ? bp[col] : 0.f;
      float cv = (EPI & EPI_CVEC) ? cvec[bctx * 256 + col] : 0.f;
#pragma unroll
      for (int r = 0; r < 4; ++r) {
        float v = acc[mi][ni][r] + bv + cv;
        if (EPI & EPI_ELU)  v = v > 0.f ? v : __expf(v) - 1.f;
        if (EPI & EPI_ATTN) { v *= 0.125f; if (col > row0 + r) v = -1e9f; }
        int srow = row0 + r;
        if constexpr (EPI & EPI_PERM) srow = perm512(srow);
        if constexpr (CF32) CbF[(size_t)srow * ldc + col] = v;
        else                CbH[(size_t)srow * ldc + col] = (bf16)v;
      }
    }
  }
}

// ---------------- fg wide kernel: 64 rows x ALL 384 cols per block, K=3072 ----------------
// grid = 384 (best measured config: 192us). A (x, f32): reg-staged T14 split.
// B = fgW1WsT (L2-resident): gload_lds. 2-phase double-buffered LDS.
__global__ __launch_bounds__(256, 2)
void fgwide_kernel(const float* __restrict__ A, const bf16* __restrict__ Bt,
                   bf16* __restrict__ C, const float* __restrict__ bias,
                   const float* __restrict__ cvec)
{
  __shared__ __align__(16) bf16 As[2][64 * 32];    // 4 KB per buffer
  __shared__ __align__(16) bf16 Bs[2][384 * 32];   // 24 KB per buffer
  const int tid = threadIdx.x;
  const int wave = tid >> 6, lane = tid & 63;      // wave = column group (96 cols)
  const int quad = lane >> 4, l16 = lane & 15;
  const int rowBase = blockIdx.x * 64;

  f32x4 acc[4][6];
#pragma unroll
  for (int i = 0; i < 4; ++i)
#pragma unroll
    for (int j = 0; j < 6; ++j) { acc[i][j][0]=0.f; acc[i][j][1]=0.f; acc[i][j][2]=0.f; acc[i][j][3]=0.f; }

  const int r1 = tid >> 2, kh = (tid & 3) * 8;     // A staging: 8 f32/thread
  const int arow = l16 * 32 + quad * 8;
  const int brow = (wave * 96 + l16) * 32 + quad * 8;

  char* BsW = (char*)&Bs[0][0] + wave * 1024;      // + c*4096: dest byte = idx*16 (linear)

  f32x4 pf0, pf1;
  int cur = 0;

  {
    const float* p = A + (size_t)(rowBase + r1) * 3072 + kh;
    pf0 = *(const f32x4*)(p); pf1 = *(const f32x4*)(p + 4);
#pragma unroll
    for (int c = 0; c < 6; ++c) {
      const int idx = c * 256 + tid, rb = idx >> 2, kc2 = idx & 3;
      gload16(Bt + (size_t)rb * 3072 + kc2 * 8, BsW + c * 4096);
    }
    bf16x8 av;
#pragma unroll
    for (int e = 0; e < 4; ++e) { av[e] = (bf16)pf0[e]; av[4 + e] = (bf16)pf1[e]; }
    *(bf16x8*)(&As[0][0] + r1 * 32 + kh) = av;
  }
  __syncthreads();

  for (int t = 0; t < 96; ++t) {
    const int nxt = cur ^ 1;
    if (t + 1 < 96) {
      const int k1 = (t + 1) * 32;
      const float* p = A + (size_t)(rowBase + r1) * 3072 + k1 + kh;
      pf0 = *(const f32x4*)(p); pf1 = *(const f32x4*)(p + 4);
#pragma unroll
      for (int c = 0; c < 6; ++c) {
        const int idx = c * 256 + tid, rb = idx >> 2, kc2 = idx & 3;
        gload16(Bt + (size_t)rb * 3072 + k1 + kc2 * 8, BsW + nxt * 24576 + c * 4096);
      }
    }

    const bf16* Asc = &As[cur][0];
    const bf16* Bsc = &Bs[cur][0];
    bf16x8 af[4], bfv[6];
#pragma unroll
    for (int mi = 0; mi < 4; ++mi) af[mi]  = *(const bf16x8*)(Asc + arow + mi * 512);
#pragma unroll
    for (int ni = 0; ni < 6; ++ni) bfv[ni] = *(const bf16x8*)(Bsc + brow + ni * 512);
#pragma unroll
    for (int mi = 0; mi < 4; ++mi)
#pragma unroll
      for (int ni = 0; ni < 6; ++ni)
        acc[mi][ni] = __builtin_amdgcn_mfma_f32_16x16x32_bf16(af[mi], bfv[ni], acc[mi][ni], 0, 0, 0);

    if (t + 1 < 96) {                              // A arrived during MFMA; write late
      bf16x8 av;
#pragma unroll
      for (int e = 0; e < 4; ++e) { av[e] = (bf16)pf0[e]; av[4 + e] = (bf16)pf1[e]; }
      *(bf16x8*)(&As[nxt][0] + r1 * 32 + kh) = av;
    }
    __syncthreads();
    cur = nxt;
  }

  const int bctx = rowBase / 384;   // 64-row tile never crosses a b boundary
#pragma unroll
  for (int mi = 0; mi < 4; ++mi) {
#pragma unroll
    for (int ni = 0; ni < 6; ++ni) {
      const int col = wave * 96 + ni * 16 + l16;
      const bool act = (wave * 96 + ni * 16) < 256;  // fragment-uniform
      const float bv = bias[col];
      const float cv = act ? cvec[bctx * 256 + col] : 0.f;
      const int row0 = rowBase + mi * 16 + quad * 4;
#pragma unroll
      for (int r = 0; r < 4; ++r) {
        float v = acc[mi][ni][r] + bv + cv;
        if (act) v = v > 0.f ? v : __expf(v) - 1.f;
        C[(size_t)(row0 + r) * 384 + col] = (bf16)v;
      }
    }
  }
}

// ---------------- wtrans: LDS-tiled coalesced weight transposes (f32 -> bf16) ----------------
// dst[n][k] = (bf16)src[k][n], 32x32 tiles. Reads 128B-coalesced, writes 64B-coalesced.
// Jobs (tile ranges): fgW1(768) fgWs->pad128(384) svW1 x12(768) svWg x12(1536)
//                     enW1(64) enWg(128) Wo(16). Total 3664 blocks.
__global__ __launch_bounds__(256)
void wtrans_kernel(const float* __restrict__ fgW1, const float* __restrict__ fgWs,
                   const float* __restrict__ svW1, const float* __restrict__ svWg,
                   const float* __restrict__ enW1, const float* __restrict__ enWg,
                   const float* __restrict__ Wo,
                   bf16* __restrict__ fgW1WsT, bf16* __restrict__ svW1T,
                   bf16* __restrict__ svWgT, bf16* __restrict__ enW1T,
                   bf16* __restrict__ enWgT, bf16* __restrict__ WoT)
{
  __shared__ float tbuf[32][33];
  int tile = blockIdx.x;
  const float* src; bf16* dst; int K, Nsrc, tk, tn;
  if (tile < 768)        { src = fgW1; dst = fgW1WsT; K = 3072; Nsrc = 256; tk = tile % 96; tn = tile / 96; }
  else if ((tile -= 768) < 384)  { src = fgWs; dst = fgW1WsT + (size_t)256 * 3072; K = 3072; Nsrc = 12;  tk = tile % 96; tn = tile / 96; }
  else if ((tile -= 384) < 768)  { int v = tile / 64,  r = tile % 64;
                                   src = svW1 + (size_t)v * 65536;  dst = svW1T + (size_t)v * 65536;  K = 256; Nsrc = 256; tk = r % 8; tn = r / 8; }
  else if ((tile -= 768) < 1536) { int v = tile / 128, r = tile % 128;
                                   src = svWg + (size_t)v * 131072; dst = svWgT + (size_t)v * 131072; K = 256; Nsrc = 512; tk = r % 8; tn = r / 8; }
  else if ((tile -= 1536) < 64)  { src = enW1; dst = enW1T; K = 256; Nsrc = 256; tk = tile % 8; tn = tile / 8; }
  else if ((tile -= 64) < 128)   { src = enWg; dst = enWgT; K = 256; Nsrc = 512; tk = tile % 8; tn = tile / 8; }
  else                           { tile -= 128; src = Wo; dst = WoT; K = 64; Nsrc = 256; tk = tile % 2; tn = tile / 2; }
  const int tx = threadIdx.x & 31, ty = threadIdx.x >> 5;
  const int k0 = tk * 32, n0 = tn * 32;
  const int n = n0 + tx;
#pragma unroll
  for (int p = 0; p < 4; ++p)
    tbuf[ty + 8 * p][tx] = (n < Nsrc) ? src[(size_t)(k0 + ty + 8 * p) * Nsrc + n] : 0.f;
  __syncthreads();
#pragma unroll
  for (int p = 0; p < 4; ++p)
    dst[(size_t)(n0 + ty + 8 * p) * K + k0 + tx] = (bf16)tbuf[tx][ty + 8 * p];
}

// ---------------- prep: remaining pads / plain casts (f32 -> bf16), one launch ----------------
__global__ void prep_kernel(
    const float* fgWg, const float* fgb1, const float* fgbs,
    const float* fgW2, const float* svW2, const float* enW2,
    const float* Wq, const float* Wk, const float* Wv,
    bf16* fgWgPT, bf16* fgW2C, float* bias384,
    bf16* svW2C, bf16* enW2C, bf16* WqkvT)
{
  long i = (long)blockIdx.x * 256 + threadIdx.x;
  if (i < 32768)  { int n = i >> 8, k = i & 255; fgWgPT[i] = (n < 24) ? (bf16)fgWg[k * 24 + n] : (bf16)0.f; return; } i -= 32768;
  if (i < 65536)  { fgW2C[i] = (bf16)fgW2[i]; return; } i -= 65536;
  if (i < 384)    { bias384[i] = (i < 256) ? fgb1[i] : ((i < 268) ? fgbs[i - 256] : 0.f); return; } i -= 384;
  if (i < 786432) { svW2C[i] = (bf16)svW2[i]; return; } i -= 786432;
  if (i < 65536)  { enW2C[i] = (bf16)enW2[i]; return; } i -= 65536;
  if (i < 163840) { int n = i >> 8, k = i & 255; float val;
                    if (n < 256)      val = Wq[(n >> 6) * 16384 + k * 64 + (n & 63)];
                    else if (n < 512) { int nn = n - 256; val = Wk[(nn >> 6) * 16384 + k * 64 + (nn & 63)]; }
                    else if (n < 576) val = Wv[k * 64 + (n - 512)];
                    else              val = 0.f;
                    WqkvT[i] = (bf16)val; }
}

// ---------------- fused bias: bF = b2@Wg + bg (f32 exact); sv/en stored PERMUTED ----------------
__global__ void biasfuse_kernel(const float* fgb2, const float* fgWg, const float* fgbg,
                                const float* svb2, const float* svWg, const float* svbg,
                                const float* enb2, const float* enWg, const float* enbg,
                                float* fgBF, float* svBFP, float* enBFP)
{
  int i = blockIdx.x * 256 + threadIdx.x;
  if (i < 128) {
    float s = 0.f;
    if (i < 24) { s = fgbg[i]; for (int k = 0; k < 256; ++k) s += fgb2[k] * fgWg[k * 24 + i]; }
    fgBF[i] = s; return; } i -= 128;
  if (i < 6144) {
    int v = i >> 9, n = i & 511;
    float s = svbg[v * 512 + n];
    const float* W = svWg + (size_t)v * 131072;
    const float* b2 = svb2 + v * 256;
    for (int k = 0; k < 256; ++k) s += b2[k] * W[k * 512 + n];
    svBFP[v * 512 + perm512(n)] = s; return; } i -= 6144;
  if (i < 512) {
    float s = enbg[i];
    for (int k = 0; k < 256; ++k) s += enb2[k] * enWg[k * 512 + i];
    enBFP[perm512(i)] = s; }
}

// ---------------- cvec[b][n] = context[b] @ Wc  (fg / en), all f32 ----------------
__global__ void cvec_kernel(const float* __restrict__ ctx, const float* __restrict__ WcFg,
                            const float* __restrict__ WcEn, float* __restrict__ outFg,
                            float* __restrict__ outEn) {
  int b = blockIdx.x, n = threadIdx.x;
  const float* Wc = blockIdx.y ? WcEn : WcFg;
  float* o = blockIdx.y ? outEn : outFg;
  float acc = 0.f;
  for (int d = 0; d < 256; ++d) acc += ctx[b * 256 + d] * Wc[d * 256 + n];
  o[b * 256 + n] = acc;
}

// ---------------- lnsm12: gate + w = softmax(LN(skip + gated)) over V=12 ----------------
__global__ void lnsm12_kernel(const bf16* __restrict__ B384, const bf16* __restrict__ GP,
                              const float* __restrict__ lng, const float* __restrict__ lnb,
                              float* __restrict__ w) {
  int r = blockIdx.x * 256 + threadIdx.x;
  if (r >= BTR) return;
  float y[12]; float m = 0.f;
#pragma unroll
  for (int j = 0; j < 12; ++j) {
    float a = (float)GP[(size_t)r * 128 + j];
    float g = (float)GP[(size_t)r * 128 + 12 + j];
    float gated = a / (1.f + __expf(-g));
    y[j] = (float)B384[(size_t)r * 384 + 256 + j] + gated; m += y[j];
  }
  m *= (1.f / 12.f);
  float var = 0.f;
#pragma unroll
  for (int j = 0; j < 12; ++j) { float d = y[j] - m; var += d * d; }
  var *= (1.f / 12.f);
  float rstd = rsqrtf(var + 1e-5f);
  float mx = -1e30f;
#pragma unroll
  for (int j = 0; j < 12; ++j) { y[j] = (y[j] - m) * rstd * lng[j] + lnb[j]; mx = fmaxf(mx, y[j]); }
  float s = 0.f;
#pragma unroll
  for (int j = 0; j < 12; ++j) { y[j] = __expf(y[j] - mx); s += y[j]; }
  float inv = 1.f / s;
#pragma unroll
  for (int j = 0; j < 12; ++j) w[r * 12 + j] = y[j] * inv;
}

// ---------------- block (256-thr) reduce of two sums ----------------
__device__ __forceinline__ void block_sum2(float a, float b, float& oa, float& ob) {
#pragma unroll
  for (int o = 32; o; o >>= 1) { a += __shfl_xor(a, o); b += __shfl_xor(b, o); }
  __shared__ float ra[4], rb[4];
  int w = threadIdx.x >> 6;
  if ((threadIdx.x & 63) == 0) { ra[w] = a; rb[w] = b; }
  __syncthreads();
  oa = ra[0] + ra[1] + ra[2] + ra[3];
  ob = rb[0] + rb[1] + rb[2] + rb[3];
  __syncthreads();
}

// ---------------- per-variable GRN tail for 4 vars: LN + weighted acc (gated precomputed) ----------------
__global__ __launch_bounds__(256)
void selacc4_kernel(const bf16* __restrict__ GATED, const float* __restrict__ x,
                    const float* __restrict__ w, const float* __restrict__ lng,
                    const float* __restrict__ lnb, float* __restrict__ sel,
                    bf16* __restrict__ selb, int v0, int isFirst, int isLast) {
  int r = blockIdx.x, d = threadIdx.x;
  float acc = isFirst ? 0.f : sel[(size_t)r * 256 + d];
#pragma unroll
  for (int vv = 0; vv < 4; ++vv) {
    int v = v0 + vv;
    float gated = (float)GATED[(size_t)vv * ((size_t)BTR * 256) + (size_t)r * 256 + d];
    float y = x[(size_t)r * 3072 + v * 256 + d] + gated;
    float s1, s2;
    block_sum2(y, y * y, s1, s2);
    float mean = s1 * (1.f / 256.f);
    float var  = s2 * (1.f / 256.f) - mean * mean;
    float val  = (y - mean) * rsqrtf(var + 1e-5f) * lng[v * 256 + d] + lnb[v * 256 + d];
    acc += w[r * 12 + v] * val;
  }
  if (isLast) selb[(size_t)r * 256 + d] = (bf16)acc;
  else        sel[(size_t)r * 256 + d] = acc;
}

// ---------------- enrichment GRN tail: LN(skip + gated) -> enr (gated precomputed) ----------------
__global__ __launch_bounds__(256)
void enrln_kernel(const bf16* __restrict__ GATED, const bf16* __restrict__ skip,
                  const float* __restrict__ lng, const float* __restrict__ lnb,
                  bf16* __restrict__ out) {
  int r = blockIdx.x, d = threadIdx.x;
  float gated = (float)GATED[(size_t)r * 256 + d];
  float y = (float)skip[(size_t)r * 256 + d] + gated;
  float s1, s2;
  block_sum2(y, y * y, s1, s2);
  float mean = s1 * (1.f / 256.f);
  float var = s2 * (1.f / 256.f) - mean * mean;
  float norm = (y - mean) * rsqrtf(var + 1e-5f);
  out[(size_t)r * 256 + d] = (bf16)(norm * lng[d] + lnb[d]);
}

// ---------------- Pbar[b,q,:] = (1/4) sum_h softmax(S[h,b,q,:]) — wave per row ----------------
__global__ __launch_bounds__(256)
void softmax_avg_kernel(const bf16* __restrict__ S, bf16* __restrict__ P) {
  const int wv = threadIdx.x >> 6, lane = threadIdx.x & 63;
  const int bq = blockIdx.x * 4 + wv;
  const int b = bq / 384, q = bq % 384;
  float pb[6];
#pragma unroll
  for (int e = 0; e < 6; ++e) pb[e] = 0.f;
  for (int h = 0; h < 4; ++h) {
    const bf16* row = S + ((size_t)((h * 64 + b) * 384 + q)) * 384;
    float v[6]; float m = -1e30f;
#pragma unroll
    for (int e = 0; e < 6; ++e) { v[e] = (float)row[lane + e * 64]; m = fmaxf(m, v[e]); }
#pragma unroll
    for (int o = 32; o; o >>= 1) m = fmaxf(m, __shfl_xor(m, o));
    float l = 0.f;
#pragma unroll
    for (int e = 0; e < 6; ++e) { v[e] = __expf(v[e] - m); l += v[e]; }
#pragma unroll
    for (int o = 32; o; o >>= 1) l += __shfl_xor(l, o);
    float inv = 1.f / l;
#pragma unroll
    for (int e = 0; e < 6; ++e) pb[e] += v[e] * inv;
  }
  bf16* out = P + (size_t)bq * 384;
#pragma unroll
  for (int e = 0; e < 6; ++e) out[lane + e * 64] = (bf16)(0.25f * pb[e]);
}

// ================= host side =================
template<int EPI, bool AF32, bool CF32, int KT = 0>
static inline void rungemm(hipStream_t s,
    const void* A, int lda, const bf16* Bt, int ldb, void* C, int ldc,
    int M, int N, int K,
    const float* bias = nullptr, const float* cvec = nullptr,
    int Z = 1, int zdiv = 1,
    long sAh = 0, long sAb = 0, long sBh = 0, long sBb = 0, long sC = 0, long sBias = 0)
{
  dim3 grid(N / 128, M / 128, Z);
  gemm_kernel<EPI, AF32, CF32, KT><<<grid, 256, 0, s>>>(A, lda, sAh, sAb, Bt, ldb, sBh, sBb, C, ldc, sC, K, zdiv, bias, cvec, sBias);
}

extern "C" void kernel_launch(void* const* d_in, const int* in_sizes, int n_in,
                              void* d_out, int out_size, void* d_ws, size_t ws_size,
                              hipStream_t stream)
{
  (void)in_sizes; (void)n_in; (void)out_size;
  const float* x      = (const float*)d_in[0];
  const float* ctx    = (const float*)d_in[1];
  const float* fg_W1  = (const float*)d_in[2];
  const float* fg_b1  = (const float*)d_in[3];
  const float* fg_Wc  = (const float*)d_in[4];
  const float* fg_W2  = (const float*)d_in[5];
  const float* fg_b2  = (const float*)d_in[6];
  const float* fg_Wg  = (const float*)d_in[7];
  const float* fg_bg  = (const float*)d_in[8];
  const float* fg_Ws  = (const float*)d_in[9];
  const float* fg_bs  = (const float*)d_in[10];
  const float* fg_lng = (const float*)d_in[11];
  const float* fg_lnb = (const float*)d_in[12];
  const float* sv_W1  = (const float*)d_in[13];
  const float* sv_b1  = (const float*)d_in[14];
  const float* sv_W2  = (const float*)d_in[15];
  const float* sv_b2  = (const float*)d_in[16];
  const float* sv_Wg  = (const float*)d_in[17];
  const float* sv_bg  = (const float*)d_in[18];
  const float* sv_lng = (const float*)d_in[19];
  const float* sv_lnb = (const float*)d_in[20];
  const float* en_W1  = (const float*)d_in[21];
  const float* en_b1  = (const float*)d_in[22];
  const float* en_Wc  = (const float*)d_in[23];
  const float* en_W2  = (const float*)d_in[24];
  const float* en_b2  = (const float*)d_in[25];
  const float* en_Wg  = (const float*)d_in[26];
  const float* en_bg  = (const float*)d_in[27];
  const float* en_lng = (const float*)d_in[28];
  const float* en_lnb = (const float*)d_in[29];
  const float* Wq     = (const float*)d_in[30];
  const float* Wk     = (const float*)d_in[31];
  const float* Wv     = (const float*)d_in[32];
  const float* Wo     = (const float*)d_in[33];

  // -------- workspace layout (bytes) --------
  static constexpr size_t OFF_FGW1WST = 0;                          // 384x3072 bf16
  static constexpr size_t OFF_FGWGPT  = OFF_FGW1WST + 2359296;      // 128x256 bf16
  static constexpr size_t OFF_FGW2C   = OFF_FGWGPT  + 65536;        // 256x256 bf16
  static constexpr size_t OFF_FGW2GT  = OFF_FGW2C   + 131072;       // 128x256 bf16
  static constexpr size_t OFF_BIAS384 = OFF_FGW2GT  + 65536;        // 384 f32
  static constexpr size_t OFF_FGBF    = OFF_BIAS384 + 1536;         // 128 f32
  static constexpr size_t OFF_SVW1T   = OFF_FGBF    + 512;          // 12x256x256 bf16
  static constexpr size_t OFF_SVWGT   = OFF_SVW1T   + 1572864;      // 12x512x256 bf16
  static constexpr size_t OFF_SVW2C   = OFF_SVWGT   + 3145728;      // 12x256x256 bf16
  static constexpr size_t OFF_SVW2GPT = OFF_SVW2C   + 1572864;      // 12x512x256 bf16 (row-permuted)
  static constexpr size_t OFF_SVBFP   = OFF_SVW2GPT + 3145728;      // 12x512 f32 (permuted)
  static constexpr size_t OFF_ENW1T   = OFF_SVBFP   + 24576;        // 256x256 bf16
  static constexpr size_t OFF_ENWGT   = OFF_ENW1T   + 131072;       // 512x256 bf16
  static constexpr size_t OFF_ENW2C   = OFF_ENWGT   + 262144;       // 256x256 bf16
  static constexpr size_t OFF_ENW2GPT = OFF_ENW2C   + 131072;       // 512x256 bf16 (row-permuted)
  static constexpr size_t OFF_ENBFP   = OFF_ENW2GPT + 262144;       // 512 f32 (permuted)
  static constexpr size_t OFF_WQKVT   = OFF_ENBFP   + 2048;         // 640x256 bf16
  static constexpr size_t OFF_WOT     = OFF_WQKVT   + 327680;       // 256x64 bf16
  static constexpr size_t OFF_CVECFG  = OFF_WOT     + 32768;        // 64x256 f32
  static constexpr size_t OFF_CVECEN  = OFF_CVECFG  + 65536;
  static constexpr size_t ARENA       = OFF_CVECEN  + 65536;        // = 13,365,248
  static constexpr size_t WS_NEEDED = ARENA + 152174592;            // ~158 MB

  if (ws_size < WS_NEEDED) return;  // fail cleanly

  char* ws = (char*)d_ws;
  bf16*  fgW1WsT = (bf16*)(ws + OFF_FGW1WST);
  bf16*  fgWgPT  = (bf16*)(ws + OFF_FGWGPT);
  bf16*  fgW2C   = (bf16*)(ws + OFF_FGW2C);
  bf16*  fgW2gT  = (bf16*)(ws + OFF_FGW2GT);
  float* bias384 = (float*)(ws + OFF_BIAS384);
  float* fgBF    = (float*)(ws + OFF_FGBF);
  bf16*  svW1T   = (bf16*)(ws + OFF_SVW1T);
  bf16*  svWgT   = (bf16*)(ws + OFF_SVWGT);
  bf16*  svW2C   = (bf16*)(ws + OFF_SVW2C);
  bf16*  svW2gPT = (bf16*)(ws + OFF_SVW2GPT);
  float* svBFP   = (float*)(ws + OFF_SVBFP);
  bf16*  enW1T   = (bf16*)(ws + OFF_ENW1T);
  bf16*  enWgT   = (bf16*)(ws + OFF_ENWGT);
  bf16*  enW2C   = (bf16*)(ws + OFF_ENW2C);
  bf16*  enW2gPT = (bf16*)(ws + OFF_ENW2GPT);
  float* enBFP   = (float*)(ws + OFF_ENBFP);
  bf16*  WqkvT   = (bf16*)(ws + OFF_WQKVT);
  bf16*  WoT     = (bf16*)(ws + OFF_WOT);
  float* cvecFg  = (float*)(ws + OFF_CVECFG);
  float* cvecEn  = (float*)(ws + OFF_CVECEN);
  char*  ar      = ws + ARENA;
  float* sel     = (float*)(ar + 0);
  bf16*  selb    = (bf16*)(ar + 25165824);
  float* wbuf    = (float*)(ar + 37748736);
  bf16*  H1G     = (bf16*)(ar + 38928384);
  bf16*  BUF384  = (bf16*)(ar + 38928384);
  bf16*  GPAD    = (bf16*)(ar + 57802752);
  bf16*  H1EN    = (bf16*)(ar + 38928384);
  bf16*  GATED   = (bf16*)(ar + 89260032);
  bf16*  GATEDEN = (bf16*)(ar + 89260032);
  bf16*  enr     = (bf16*)(ar + 139591680);
  bf16*  QKV     = (bf16*)(ar + 0);
  bf16*  Pbar    = (bf16*)(ar + 38928384);
  bf16*  Sbuf    = (bf16*)(ar + 64094208);
  bf16*  UT      = (bf16*)(ar + 64094208);
  float* out     = (float*)d_out;

  // 1) weight prep: coalesced tiled transposes + remaining pads/casts
  wtrans_kernel<<<3664, 256, 0, stream>>>(fg_W1, fg_Ws, sv_W1, sv_Wg, en_W1, en_Wg, Wo,
                                          fgW1WsT, svW1T, svWgT, enW1T, enWgT, WoT);
  prep_kernel<<<4354, 256, 0, stream>>>(fg_Wg, fg_b1, fg_bs, fg_W2, sv_W2, en_W2,
                                        Wq, Wk, Wv,
                                        fgWgPT, fgW2C, bias384, svW2C, enW2C, WqkvT);
  // 2) fused biases (sv/en permuted) + context vectors
  biasfuse_kernel<<<27, 256, 0, stream>>>(fg_b2, fg_Wg, fg_bg, sv_b2, sv_Wg, sv_bg,
                                          en_b2, en_Wg, en_bg, fgBF, svBFP, enBFP);
  cvec_kernel<<<dim3(64, 2), 256, 0, stream>>>(ctx, fg_Wc, en_Wc, cvecFg, cvecEn);

  // 3) combined weights W2g[n][k2] = sum_k Wg[k][n]*W2[k2][k]; sv/en rows stored permuted
  rungemm<0,        false, false, 256>(stream, fgWgPT, 256, fgW2C, 256, fgW2gT, 256, 128, 256, 256);
  rungemm<EPI_PERM, false, false, 256>(stream, svWgT, 256, svW2C, 256, svW2gPT, 256, 512, 256, 256,
                                       nullptr, nullptr, 12, 12, 0, 131072, 0, 65536, 131072);
  rungemm<EPI_PERM, false, false, 256>(stream, enWgT, 256, enW2C, 256, enW2gPT, 256, 512, 256, 256);

  // 4) flattened GRN: wide-tile fused [h1 | skip] GEMM (x read once), g GEMM, LN+softmax
  fgwide_kernel<<<384, 256, 0, stream>>>(x, fgW1WsT, BUF384, bias384, cvecFg);
  rungemm<EPI_BIAS, false, false, 256>(stream, BUF384, 384, fgW2gT, 256, GPAD, 128, BTR, 128, 256, fgBF);
  lnsm12_kernel<<<96, 256, 0, stream>>>(BUF384, GPAD, fg_lng, fg_lnb, wbuf);

  // 5) per-variable GRNs, batched Z=4 (3 groups), gate fused in W2g epilogue
  for (int g = 0; g < 3; ++g) {
    rungemm<EPI_BIAS|EPI_ELU, true, false>(
        stream, x + g * 4 * 256, 3072, svW1T + (size_t)g * 4 * 65536, 256, H1G, 256, BTR, 256, 256,
        sv_b1 + g * 4 * 256, nullptr, 4, 4, 0, 256, 0, 65536, (long)BTR * 256, 256);
    rungemm<EPI_BIAS|EPI_GATE, false, false, 256>(
        stream, H1G, 256, svW2gPT + (size_t)g * 4 * 131072, 256, GATED, 256, BTR, 512, 256,
        svBFP + g * 4 * 512, nullptr, 4, 4, 0, (long)BTR * 256, 0, 131072, (long)BTR * 256, 512);
    selacc4_kernel<<<BTR, 256, 0, stream>>>(GATED, x, wbuf, sv_lng, sv_lnb, sel, selb,
                                            g * 4, g == 0, g == 2);
  }

  // 6) enrichment GRN (gate fused)
  rungemm<EPI_BIAS|EPI_CVEC|EPI_ELU, false, false, 256>(stream, selb, 256, enW1T, 256, H1EN, 256, BTR, 256, 256, en_b1, cvecEn);
  rungemm<EPI_BIAS|EPI_GATE, false, false, 256>(stream, H1EN, 256, enW2gPT, 256, GATEDEN, 256, BTR, 512, 256, enBFP);
  enrln_kernel<<<BTR, 256, 0, stream>>>(GATEDEN, selb, en_lng, en_lnb, enr);

  // 7) attention
  rungemm<0, false, false, 256>(stream, enr, 256, WqkvT, 256, QKV, 640, BTR, 640, 256);
  rungemm<EPI_ATTN, false, false, 64>(stream, QKV, 640, QKV + 256, 640, Sbuf, 384, 384, 384, 64,
                                      nullptr, nullptr, 256, 64, 64, 245760L, 64, 245760L, 147456L);
  softmax_avg_kernel<<<6144, 256, 0, stream>>>(Sbuf, Pbar);
  // UT[b][d][t] = sum_k Wo[k][d] * vp_b[t][k]  (direct transposed U)
  rungemm<0, false, false, 64>(stream, WoT, 64, QKV + 512, 640, UT, 384, 256, 384, 64,
                               nullptr, nullptr, 64, 64, 0, 0, 0, 245760L, 98304L);
  // out[b] = Pbar[b] @ UT[b]^T, batched over b -> f32 d_out
  rungemm<0, false, true>(stream, Pbar, 384, UT, 384, out, 256, 384, 256, 384,
                          nullptr, nullptr, 64, 1, 147456L, 0, 98304L, 0, 98304L);
}